// Round 13
// baseline (187.691 us; speedup 1.0000x reference)
//
#include <hip/hip_runtime.h>

// MHSA: B=2, S=2048, D=1024, H=16, dk=64.  bf16-MFMA pipeline, fp32 accumulate.
// qkv is COLUMN-PERMUTED to [Q(1024) | K(1024) | V(1024)] via wqkvT row perm:
// attn reads Q at col h*64, K at 1024+h*64; V never lands in qkv (the V-blocks
// of the qkv GEMM write vt[bh][dk][s] directly in their epilogue).
#define SS 2048
#define DD 1024
#define N3 3072

typedef unsigned short u16;
typedef unsigned int u32;
typedef __attribute__((ext_vector_type(8))) short bf16x8;   // MFMA A/B frag (4 VGPR)
typedef __attribute__((ext_vector_type(4))) short bf16x4;   // 16x16x16 A/B frag (2 VGPR)
typedef __attribute__((ext_vector_type(4))) float f32x4;    // MFMA C/D frag

__device__ __forceinline__ u16 f2bf(float f) {   // round-to-nearest-even bf16
    u32 u = __float_as_uint(f);
    u32 r = u + 0x7fffu + ((u >> 16) & 1u);
    return (u16)(r >> 16);
}

__device__ __forceinline__ float fast_exp2(float x) {
    return __builtin_amdgcn_exp2f(x);   // v_exp_f32: D = 2^S0
}

__device__ __forceinline__ void async_cp16(u16* lds, const u16* g) {
    __builtin_amdgcn_global_load_lds((const __attribute__((address_space(1))) u32*)g,
                                     (__attribute__((address_space(3))) u32*)lds, 16, 0, 0);
}

// v_mfma_f32_16x16x16_bf16 (gfx90a+ "_1k" builtin name; A/B = 4 x i16)
__device__ __forceinline__ f32x4 mfma16(bf16x4 a, bf16x4 b, f32x4 c) {
    return __builtin_amdgcn_mfma_f32_16x16x16bf16_1k(a, b, c, 0, 0, 0);
}

// ---------------------------------------------------------------------------
// Fused preprocessing, one launch (8192 blocks x 256 thr):
//   bx <  4096       : x = bf16(query + pos_emb), 4 elems/thread
//   4096 <= bx <7168 : w_qkv [1024,3072] -> wqkvT [perm(n)][1024] bf16:
//                      perm maps col h*192+r to Q|K|V-blocked layout; Q rows
//                      (dst<1024) pre-scaled by dk^-0.5*log2(e)
//   7168 <= bx       : w_out [1024,1024] -> woutT [1024,1024] bf16
// ---------------------------------------------------------------------------
__global__ __launch_bounds__(256)
void prep_all(const float* __restrict__ q, const float* __restrict__ pos,
              const float* __restrict__ wqkv, const float* __restrict__ wout,
              u16* __restrict__ x, u16* __restrict__ wqkvT, u16* __restrict__ woutT)
{
    __shared__ float t[32][33];
    const int bx = blockIdx.x;

    if (bx < 4096) {
        const size_t i = ((size_t)bx * 256 + threadIdx.x) * 4;
        float4 a = *(const float4*)(q + i);
        float4 p = *(const float4*)(pos + (i & (size_t)(SS * DD - 1)));
        uint2 r;
        r.x = (u32)f2bf(a.x + p.x) | ((u32)f2bf(a.y + p.y) << 16);
        r.y = (u32)f2bf(a.z + p.z) | ((u32)f2bf(a.w + p.w) << 16);
        *(uint2*)(x + i) = r;
        return;
    }

    const int isq = bx < 7168;
    const int tt  = isq ? (bx - 4096) : (bx - 7168);
    const int nx  = isq ? 96 : 32;                    // N/32
    const int N   = isq ? N3 : DD;
    const float* W = isq ? wqkv : wout;
    u16* WT = isq ? wqkvT : woutT;

    const int x0 = (tt % nx) * 32, y0 = (tt / nx) * 32;
    const int tx = threadIdx.x & 31, ty = threadIdx.x >> 5;  // 32 x 8
#pragma unroll
    for (int i = 0; i < 4; ++i)
        t[ty + i * 8][tx] = W[(size_t)(y0 + ty + i * 8) * N + x0 + tx];
    __syncthreads();
#pragma unroll
    for (int i = 0; i < 4; ++i) {
        const int n = x0 + ty + i * 8;
        int dst = n;
        if (isq) {                                    // Q|K|V column-blocking
            const int hh = n / 192, r = n % 192;
            dst = (r < 64) ? hh * 64 + r
                : (r < 128) ? 1024 + hh * 64 + (r - 64)
                            : 2048 + hh * 64 + (r - 128);
        }
        float v = t[tx][ty + i * 8];
        if (isq && dst < 1024) v *= 0.18033688f;      // 0.125 * log2(e)
        WT[(size_t)dst * DD + y0 + tx] = f2bf(v);
    }
}

// ---------------------------------------------------------------------------
// 256x256 deep-pipelined GEMM (qkv):  C[M,N] = A[M,K] * B[K,N].
// BK=64, 8 waves (2M x 4N), per-wave C 128x64 (acc 8x4).  ONE barrier per
// K-tile, prefetch-after-barrier; LDS XOR-swizzled 16B chunks via gload src.
// Epilogue split:
//   n0 <  2048 (Q/K blocks): normal bf16 C-write into qkv.
//   n0 >= 2048 (V blocks)  : NO C-write; transpose 256x256 tile through LDS
//     and write vt[(b*16+h)*64+dk][s] coalesced.  Replaces transpose_v.
// XCD swizzle: 1D grid (nwg%8==0), chunk = nwg/8.
// LDS: 135168 B dynamic (main loop uses first 128 KiB).
// ---------------------------------------------------------------------------
__global__ __launch_bounds__(512, 2)
void gemm256(const u16* __restrict__ A, const u16* __restrict__ BT,
             u16* __restrict__ C, u16* __restrict__ vt, int M, int N, int K, int nbx)
{
    extern __shared__ __align__(16) u16 smem[];

    const int bid = blockIdx.x;
    const int chunk = (int)gridDim.x >> 3;
    const int swz = (bid & 7) * chunk + (bid >> 3);
    const int bxs = swz % nbx, bys = swz / nbx;

    const int tid = threadIdx.x;
    const int lane = tid & 63;
    const int wv = tid >> 6;
    const int quad = lane >> 4, l16 = lane & 15;
    const int wm = wv >> 2, wn = wv & 3;          // 2 x 4 wave grid
    const int m0 = bys * 256, n0 = bxs * 256;
    const int sw = l16 & 7;

    // staging map: per call 512 thr x 16B = 8 KiB = 64 rows of 128B.
    const int srow = tid >> 3, pc = tid & 7, lc = pc ^ (srow & 7);
    const u16* agp = A  + (size_t)(m0 + srow) * K + lc * 8;
    const u16* bgp = BT + (size_t)(n0 + srow) * K + lc * 8;
    u16* const asw = smem +         srow * 64 + pc * 8;   // + buf*16384 + s*4096
    u16* const bsw = smem + 32768 + srow * 64 + pc * 8;

    auto stage = [&](int buf, int k0) {
#pragma unroll
        for (int s = 0; s < 4; ++s)
            async_cp16(asw + buf * 16384 + s * 4096, agp + (size_t)(s * 64) * K + k0);
#pragma unroll
        for (int s = 0; s < 4; ++s)
            async_cp16(bsw + buf * 16384 + s * 4096, bgp + (size_t)(s * 64) * K + k0);
    };

    f32x4 acc[8][4];
#pragma unroll
    for (int i = 0; i < 8; ++i)
#pragma unroll
        for (int j = 0; j < 4; ++j) acc[i][j] = {0.f, 0.f, 0.f, 0.f};

    stage(0, 0);   // prologue

    const int NT = K / 64;
    for (int t = 0; t < NT; ++t) {
        const int p = t & 1;
        asm volatile("s_waitcnt vmcnt(0) lgkmcnt(0)\n\ts_barrier" ::: "memory");
        if (t + 1 < NT) stage(p ^ 1, (t + 1) * 64);

        const u16* Ab = smem +         p * 16384;
        const u16* Bb = smem + 32768 + p * 16384;

#pragma unroll
        for (int ks = 0; ks < 2; ++ks) {
            bf16x8 bfr[4];
#pragma unroll
            for (int nt = 0; nt < 4; ++nt)
                bfr[nt] = *(const bf16x8*)&Bb[(wn * 64 + nt * 16 + l16) * 64 + (((ks * 4 + quad) ^ sw) << 3)];
#pragma unroll
            for (int mt = 0; mt < 8; ++mt) {
                bf16x8 af = *(const bf16x8*)&Ab[(wm * 128 + mt * 16 + l16) * 64 + (((ks * 4 + quad) ^ sw) << 3)];
#pragma unroll
                for (int nt = 0; nt < 4; ++nt)
                    acc[mt][nt] = __builtin_amdgcn_mfma_f32_16x16x32_bf16(af, bfr[nt], acc[mt][nt], 0, 0, 0);
            }
        }
    }

    if (vt && n0 >= 2048) {
        // ---- V block: transpose through LDS, write vt only ----
        __syncthreads();   // all waves done with K-loop LDS reads
        u16* tb = smem;    // vtile[v_local][m_local], row stride 264 u16
#pragma unroll
        for (int mt = 0; mt < 8; ++mt)
#pragma unroll
            for (int nt = 0; nt < 4; ++nt) {
                const int vl = wn * 64 + nt * 16 + l16;
                const int ml = wm * 128 + mt * 16 + quad * 4;
                uint2 w;
                w.x = (u32)f2bf(acc[mt][nt][0]) | ((u32)f2bf(acc[mt][nt][1]) << 16);
                w.y = (u32)f2bf(acc[mt][nt][2]) | ((u32)f2bf(acc[mt][nt][3]) << 16);
                *(uint2*)(tb + (size_t)vl * 264 + ml) = w;
            }
        __syncthreads();
        const int vl = tid >> 1, half = tid & 1;
        const int b16 = (m0 >> 11) * 16;                 // batch*16
        const int hh = ((n0 - 2048) >> 6) + (vl >> 6);   // head
        const int dk = vl & 63;
        u16* dst = vt + ((size_t)(b16 + hh) * 64 + dk) * SS + (m0 & 2047) + half * 128;
        const u16* src = tb + (size_t)vl * 264 + half * 128;
#pragma unroll
        for (int j = 0; j < 16; ++j)
            *(uint4*)(dst + j * 8) = *(const uint4*)(src + j * 8);
    } else {
        // ---- Q/K block: normal bf16 C-write ----
#pragma unroll
        for (int mt = 0; mt < 8; ++mt)
#pragma unroll
            for (int r = 0; r < 4; ++r) {
                const size_t row = m0 + wm * 128 + mt * 16 + quad * 4 + r;
                u16* cp = C + row * N + n0 + wn * 64 + l16;
#pragma unroll
                for (int nt = 0; nt < 4; ++nt) cp[nt * 16] = f2bf(acc[mt][nt][r]);
            }
    }
}

// ---------------------------------------------------------------------------
// Out-projection GEMM on the 1-barrier dbuf schedule (R11, passing).
// BM=128 x BN=NT, BK=64, 4 waves.  Double-buffered LDS (48 KiB at NT=64 ->
// 3 blocks/CU); prefetch(t+1) issued AFTER barrier(t).
// 1D grid + XCD swizzle (nwg%8==0).
// ---------------------------------------------------------------------------
template <int OUT_BF16, int NT>
__global__ __launch_bounds__(256)
void gemm_mfma(const u16* __restrict__ A, const u16* __restrict__ BT,
               void* __restrict__ Cv, int M, int N, int K, int nbx)
{
    constexpr int FR = NT / 32;    // B frags per wave per ks
    __shared__ u16 As[2][128 * 64];   // [m][64] swizzled, dbuf
    __shared__ u16 Bs[2][NT * 64];    // [n][64] swizzled, dbuf

    const int bid = blockIdx.x;
    const int chunk = (int)gridDim.x >> 3;
    const int swz = (bid & 7) * chunk + (bid >> 3);
    const int bxs = swz % nbx, bys = swz / nbx;

    const int tid = threadIdx.x;
    const int lane = tid & 63, wv = tid >> 6;
    const int quad = lane >> 4, l16 = lane & 15;
    const int m0 = bys * 128, n0 = bxs * NT;

    const int arow = wv * 32 + (lane >> 3);
    const int pc   = lane & 7;
    const int lcA  = pc ^ (arow & 7);
    const u16* agp = A + (size_t)(m0 + arow) * K + lcA * 8;

    const int brow = (NT == 128) ? (wv * 32 + (lane >> 3)) : (wv * 8 + (lane >> 3));
    const int lcB  = pc ^ (brow & 7);
    const u16* bgp = BT + (size_t)(n0 + brow) * K + lcB * 8;

    const int aoff = arow * 64 + pc * 8;
    const int boff = brow * 64 + pc * 8;

    auto stage = [&](int buf, int k0) {
#pragma unroll
        for (int s = 0; s < 4; ++s)
            async_cp16(&As[buf][aoff + s * 8 * 64], agp + (size_t)(s * 8) * K + k0);
        if constexpr (NT == 128) {
#pragma unroll
            for (int s = 0; s < 4; ++s)
                async_cp16(&Bs[buf][boff + s * 8 * 64], bgp + (size_t)(s * 8) * K + k0);
        } else {
#pragma unroll
            for (int s = 0; s < 2; ++s)
                async_cp16(&Bs[buf][boff + s * 32 * 64], bgp + (size_t)(s * 32) * K + k0);
        }
    };

    const int moff = (wv >> 1) * 64, noff = (wv & 1) * (NT / 2);

    f32x4 acc[4][FR];
#pragma unroll
    for (int i = 0; i < 4; ++i)
#pragma unroll
        for (int j = 0; j < FR; ++j) acc[i][j] = {0.f, 0.f, 0.f, 0.f};

    const int swf = l16 & 7;   // frag-read swizzle key

    stage(0, 0);   // prologue

    const int NTILES = K / 64;
    for (int t = 0; t < NTILES; ++t) {
        const int p = t & 1;
        // stage(t) drained (issued a full K-tile of compute ago); prior reads done
        asm volatile("s_waitcnt vmcnt(0) lgkmcnt(0)\n\ts_barrier" ::: "memory");
        if (t + 1 < NTILES) stage(p ^ 1, (t + 1) * 64);

        const u16* Ab = As[p];
        const u16* Bb = Bs[p];

#pragma unroll
        for (int ks = 0; ks < 2; ++ks) {
            bf16x8 af[4], bfr[FR];
#pragma unroll
            for (int tt = 0; tt < 4; ++tt)
                af[tt] = *(const bf16x8*)&Ab[(moff + tt * 16 + l16) * 64 + (((ks * 4 + quad) ^ swf) << 3)];
#pragma unroll
            for (int tt = 0; tt < FR; ++tt)
                bfr[tt] = *(const bf16x8*)&Bb[(noff + tt * 16 + l16) * 64 + (((ks * 4 + quad) ^ swf) << 3)];
#pragma unroll
            for (int mt = 0; mt < 4; ++mt)
#pragma unroll
                for (int nt = 0; nt < FR; ++nt)
                    acc[mt][nt] = __builtin_amdgcn_mfma_f32_16x16x32_bf16(af[mt], bfr[nt], acc[mt][nt], 0, 0, 0);
        }
    }

    // D layout: row = quad*4+reg, col = l16 (within each 16x16 frag)
#pragma unroll
    for (int mt = 0; mt < 4; ++mt)
#pragma unroll
        for (int r = 0; r < 4; ++r) {
            const size_t row = m0 + moff + mt * 16 + quad * 4 + r;
            if (OUT_BF16) {
                u16* cp = (u16*)Cv + row * N + n0 + noff + l16;
#pragma unroll
                for (int nt = 0; nt < FR; ++nt) cp[nt * 16] = f2bf(acc[mt][nt][r]);
            } else {
                float* cp = (float*)Cv + row * N + n0 + noff + l16;
#pragma unroll
                for (int nt = 0; nt < FR; ++nt) cp[nt * 16] = acc[mt][nt][r];
            }
        }
}

// ---------------------------------------------------------------------------
// MFMA flash attention, column-blocked qkv.  R13 change: FULL per-kn fusion —
// for each kn: {2 kf reads -> 4 QK MFMA -> exp2/pack -> 8 PV MFMA}.  sf live
// range drops from 32 regs (sf[2][4] held across the QK cluster) to 8,
// freeing ~24 regs so the allocator can hoist per-iter address math instead
// of rematerializing it (R12 showed VALU-busy ~6x the source-level op count
// at a saturated 128-reg budget).  QK MFMAs of kn+1 pipeline under PV MFMAs
// of kn.  Same math, layouts, and sync as R12 (passing, 48.0 us).
// ---------------------------------------------------------------------------
__global__ __launch_bounds__(512, 4)
void attn_mfma(const u16* __restrict__ qkv, const u16* __restrict__ vt, u16* __restrict__ o)
{
    __shared__ __align__(16) u16 smem[32768];   // 64 KiB flat; Ks: [grp*2+p]*4096, Vs: +16384

    const int tid = threadIdx.x;
    const int lane = tid & 63, wv = tid >> 6;       // 8 waves
    const int grp = wv >> 2, w4 = wv & 3;
    const int quad = lane >> 4, l16 = lane & 15;
    const int bx = blockIdx.x;
    const int bh = bx & 31, qt = bx >> 5;
    const int h = bh & 15, b = bh >> 4;

    const size_t base = (size_t)b * SS * N3;
    const int q0 = qt * 128 + w4 * 32;
    const int sw = l16 & 7;          // row-swizzle key for frag reads

    // Q frags (A-operand: m=l16, k=quad*8+j), [mtile][kstep] — pre-scaled Q
    bf16x8 qf[2][2];
#pragma unroll
    for (int mt = 0; mt < 2; ++mt)
#pragma unroll
        for (int ks = 0; ks < 2; ++ks)
            qf[mt][ks] = *(const bf16x8*)(qkv + base + h * 64 + (size_t)(q0 + mt * 16 + l16) * N3 + ks * 32 + quad * 8);

    f32x4 po[2][4];   // O^T accum: [q-blk mt][d-blk nt], d=quad*4+r, q=l16
#pragma unroll
    for (int mt = 0; mt < 2; ++mt)
#pragma unroll
        for (int nt = 0; nt < 4; ++nt) po[mt][nt] = {0.f, 0.f, 0.f, 0.f};
    float lrun[2] = {0.f, 0.f};

    // staging map: per call 64 lanes x 16B = 8 rows of 128B; lane -> row lrow,
    // phys chunk pc8; swizzle folded into SOURCE: logical chunk = pc8 ^ (row&7).
    const int lrow = lane >> 3, pc8 = lane & 7, lc = pc8 ^ lrow;
    const int srow = w4 * 16;
    const int kt0 = grp * 16;        // this group's first k-tile

    const u16* kgp = qkv + base + 1024 + h * 64 + (size_t)(kt0 * 64 + srow + lrow) * N3 + lc * 8;
    const u16* vgp = vt + ((size_t)bh * 64 + srow + lrow) * SS + kt0 * 64 + lc * 8;

    u16* const ksA = smem + (grp * 2) * 4096 + (srow + lrow) * 64 + pc8 * 8;
    u16* const ksB = ksA + 4096;
    u16* const vsA = smem + 16384 + (grp * 2) * 4096 + (srow + lrow) * 64 + pc8 * 8;
    u16* const vsB = vsA + 4096;

    // prologue: stage tile kt0 into buffer A
    async_cp16(ksA,       kgp);
    async_cp16(ksA + 512, kgp + (size_t)8 * N3);
    async_cp16(vsA,       vgp);
    async_cp16(vsA + 512, vgp + (size_t)8 * SS);

    for (int it = 0; it < 16; ++it) {
        const int p = it & 1;
        // stage(it) done (issued a full tile ago); all waves past PV(it-1)
        asm volatile("s_waitcnt vmcnt(0) lgkmcnt(0)\n\ts_barrier" ::: "memory");
        if (it < 15) {
            const size_t ko = (size_t)(it + 1) * 64;
            u16* kb = p ? ksA : ksB;
            u16* vb = p ? vsA : vsB;
            async_cp16(kb,       kgp + ko * N3);
            async_cp16(kb + 512, kgp + ko * N3 + (size_t)8 * N3);
            async_cp16(vb,       vgp + ko);
            async_cp16(vb + 512, vgp + ko + (size_t)8 * SS);
        }
        const u16* kbuf = smem + (grp * 2 + p) * 4096;
        const u16* vbuf = smem + 16384 + (grp * 2 + p) * 4096;

        // ---- fully fused per-kn: QK (2 MFMA/mt) -> exp2/pack -> PV (4/mt).
        // sf live range = 8 regs (one kn at a time); QK of kn+1 overlaps PV
        // of kn in the wave's pipe; exp2 (VALU) overlaps MFMA throughout.
        __builtin_amdgcn_s_setprio(1);
#pragma unroll
        for (int kn = 0; kn < 4; ++kn) {
            const bf16x8 kf0 = *(const bf16x8*)&kbuf[(kn * 16 + l16) * 64 + ((quad ^ sw) << 3)];
            const bf16x8 kf1 = *(const bf16x8*)&kbuf[(kn * 16 + l16) * 64 + (((4 + quad) ^ sw) << 3)];
            bf16x4 vf[4];
#pragma unroll
            for (int nt = 0; nt < 4; ++nt)
                vf[nt] = *(const bf16x4*)&vbuf[(nt * 16 + l16) * 64 + (((2 * kn + (quad >> 1)) ^ sw) << 3) + ((quad & 1) << 2)];
#pragma unroll
            for (int mt = 0; mt < 2; ++mt) {
                f32x4 s = {0.f, 0.f, 0.f, 0.f};
                s = __builtin_amdgcn_mfma_f32_16x16x32_bf16(kf0, qf[mt][0], s, 0, 0, 0);
                s = __builtin_amdgcn_mfma_f32_16x16x32_bf16(kf1, qf[mt][1], s, 0, 0, 0);
                const float p0 = fast_exp2(s[0]);
                const float p1 = fast_exp2(s[1]);
                const float p2 = fast_exp2(s[2]);
                const float p3 = fast_exp2(s[3]);
                lrun[mt] += (p0 + p1) + (p2 + p3);
                union { bf16x4 v; u32 w[2]; } pu;
                pu.w[0] = __builtin_amdgcn_perm(__float_as_uint(p1), __float_as_uint(p0), 0x07060302u);
                pu.w[1] = __builtin_amdgcn_perm(__float_as_uint(p3), __float_as_uint(p2), 0x07060302u);
#pragma unroll
                for (int nt = 0; nt < 4; ++nt)
                    po[mt][nt] = mfma16(vf[nt], pu.v, po[mt][nt]);
            }
        }
        __builtin_amdgcn_s_setprio(0);
    }

    __syncthreads();   // all K/V reads done; smem reusable as f32 scratch

    // quad-reduce l (keys split across quads) — both groups
#pragma unroll
    for (int mt = 0; mt < 2; ++mt) {
        lrun[mt] += __shfl_xor(lrun[mt], 16, 64);
        lrun[mt] += __shfl_xor(lrun[mt], 32, 64);
    }

    // cross-group combine: group 1 -> LDS -> group 0 adds
    float* xch = (float*)smem;       // [w4*64+lane][36] f32, 36 KiB
    if (grp == 1) {
        float* d = xch + (w4 * 64 + lane) * 36;
#pragma unroll
        for (int mt = 0; mt < 2; ++mt)
#pragma unroll
            for (int nt = 0; nt < 4; ++nt)
                *(f32x4*)(d + mt * 16 + nt * 4) = po[mt][nt];
        d[32] = lrun[0]; d[33] = lrun[1];
    }
    __syncthreads();
    if (grp == 0) {
        const float* s = xch + (w4 * 64 + lane) * 36;
#pragma unroll
        for (int mt = 0; mt < 2; ++mt)
#pragma unroll
            for (int nt = 0; nt < 4; ++nt)
                po[mt][nt] = po[mt][nt] + *(const f32x4*)(s + mt * 16 + nt * 4);
        lrun[0] += s[32]; lrun[1] += s[33];

        // O^T frag: q = l16 (lane-uniform l), d = nt*16 + quad*4 + r
#pragma unroll
        for (int mt = 0; mt < 2; ++mt) {
            const float linv = 1.f / lrun[mt];
            const size_t row = (size_t)b * SS + q0 + mt * 16 + l16;
#pragma unroll
            for (int nt = 0; nt < 4; ++nt) {
                const u32 h0 = (u32)f2bf(po[mt][nt][0] * linv) | ((u32)f2bf(po[mt][nt][1] * linv) << 16);
                const u32 h1 = (u32)f2bf(po[mt][nt][2] * linv) | ((u32)f2bf(po[mt][nt][3] * linv) << 16);
                uint2 wp; wp.x = h0; wp.y = h1;
                *(uint2*)(o + row * DD + h * 64 + nt * 16 + quad * 4) = wp;
            }
        }
    }
}

// ---------------------------------------------------------------------------
extern "C" void kernel_launch(void* const* d_in, const int* in_sizes, int n_in,
                              void* d_out, int out_size, void* d_ws, size_t ws_size,
                              hipStream_t stream)
{
    const float* query  = (const float*)d_in[0];
    const float* posemb = (const float*)d_in[1];
    const float* w_qkv  = (const float*)d_in[2];
    const float* w_out  = (const float*)d_in[3];
    float* out = (float*)d_out;

    u16* xb    = (u16*)d_ws;                       // [4096,1024] bf16
    u16* wqkvT = xb    + (size_t)4096 * 1024;      // [3072,1024] (row-permuted)
    u16* woutT = wqkvT + (size_t)3072 * 1024;      // [1024,1024]
    u16* qkv   = woutT + (size_t)1024 * 1024;      // [4096,3072] Q|K|(V unused)
    u16* ob    = qkv   + (size_t)4096 * 3072;      // [4096,1024]
    u16* vtb   = ob    + (size_t)4096 * 1024;      // [32,64,2048] V^T

    // allow 132 KiB dynamic LDS for gemm256 (one-time, host-side, capture-safe)
    static bool lds_init = false;
    if (!lds_init) {
        hipFuncSetAttribute((const void*)gemm256,
                            hipFuncAttributeMaxDynamicSharedMemorySize, 135168);
        lds_init = true;
    }

    // fused: prep_x + both weight transposes (wqkvT rows permuted to Q|K|V)
    prep_all<<<8192, 256, 0, stream>>>(query, posemb, w_qkv, w_out, xb, wqkvT, woutT);

    // qkv = x @ w_qkv (M=4096, N=3072, K=1024): Q/K -> qkv, V -> vt (transposed)
    gemm256<<<192, 512, 135168, stream>>>(xb, wqkvT, qkv, vtb, 4096, N3, DD, N3 / 256);

    // flash attention -> ob [4096,1024] bf16  (512 blocks x 512 thr, key-split)
    attn_mfma<<<dim3(512, 1, 1), 512, 0, stream>>>(qkv, vtb, ob);

    // out = ob @ w_out  (M=4096, N=1024, K=1024), fp32 out, 1-barrier dbuf
    gemm_mfma<0, 64><<<512, 256, 0, stream>>>(ob, woutT, (void*)out, 4096, DD, DD, DD / 64);
}

// Round 14
// 178.848 us; speedup vs baseline: 1.0494x; 1.0494x over previous
//
#include <hip/hip_runtime.h>

// MHSA: B=2, S=2048, D=1024, H=16, dk=64.  bf16-MFMA pipeline, fp32 accumulate.
// qkv is COLUMN-PERMUTED to [Q(1024) | K(1024) | V(1024)] via wqkvT row perm:
// attn reads Q at col h*64, K at 1024+h*64; V never lands in qkv (the V-blocks
// of the qkv GEMM write vt[bh][dk][s] directly in their epilogue).
#define SS 2048
#define DD 1024
#define N3 3072

typedef unsigned short u16;
typedef unsigned int u32;
typedef __attribute__((ext_vector_type(8))) short bf16x8;   // MFMA A/B frag (4 VGPR)
typedef __attribute__((ext_vector_type(4))) short bf16x4;   // 16x16x16 A/B frag (2 VGPR)
typedef __attribute__((ext_vector_type(4))) float f32x4;    // MFMA C/D frag

__device__ __forceinline__ u16 f2bf(float f) {   // round-to-nearest-even bf16
    u32 u = __float_as_uint(f);
    u32 r = u + 0x7fffu + ((u >> 16) & 1u);
    return (u16)(r >> 16);
}

__device__ __forceinline__ float fast_exp2(float x) {
    return __builtin_amdgcn_exp2f(x);   // v_exp_f32: D = 2^S0
}

__device__ __forceinline__ void async_cp16(u16* lds, const u16* g) {
    __builtin_amdgcn_global_load_lds((const __attribute__((address_space(1))) u32*)g,
                                     (__attribute__((address_space(3))) u32*)lds, 16, 0, 0);
}

// v_mfma_f32_16x16x16_bf16 (gfx90a+ "_1k" builtin name; A/B = 4 x i16)
__device__ __forceinline__ f32x4 mfma16(bf16x4 a, bf16x4 b, f32x4 c) {
    return __builtin_amdgcn_mfma_f32_16x16x16bf16_1k(a, b, c, 0, 0, 0);
}

// ---------------------------------------------------------------------------
// Fused preprocessing, one launch (8192 blocks x 256 thr):
//   bx <  4096       : x = bf16(query + pos_emb), 4 elems/thread
//   4096 <= bx <7168 : w_qkv [1024,3072] -> wqkvT [perm(n)][1024] bf16:
//                      perm maps col h*192+r to Q|K|V-blocked layout; Q rows
//                      (dst<1024) pre-scaled by dk^-0.5*log2(e)
//   7168 <= bx       : w_out [1024,1024] -> woutT [1024,1024] bf16
// ---------------------------------------------------------------------------
__global__ __launch_bounds__(256)
void prep_all(const float* __restrict__ q, const float* __restrict__ pos,
              const float* __restrict__ wqkv, const float* __restrict__ wout,
              u16* __restrict__ x, u16* __restrict__ wqkvT, u16* __restrict__ woutT)
{
    __shared__ float t[32][33];
    const int bx = blockIdx.x;

    if (bx < 4096) {
        const size_t i = ((size_t)bx * 256 + threadIdx.x) * 4;
        float4 a = *(const float4*)(q + i);
        float4 p = *(const float4*)(pos + (i & (size_t)(SS * DD - 1)));
        uint2 r;
        r.x = (u32)f2bf(a.x + p.x) | ((u32)f2bf(a.y + p.y) << 16);
        r.y = (u32)f2bf(a.z + p.z) | ((u32)f2bf(a.w + p.w) << 16);
        *(uint2*)(x + i) = r;
        return;
    }

    const int isq = bx < 7168;
    const int tt  = isq ? (bx - 4096) : (bx - 7168);
    const int nx  = isq ? 96 : 32;                    // N/32
    const int N   = isq ? N3 : DD;
    const float* W = isq ? wqkv : wout;
    u16* WT = isq ? wqkvT : woutT;

    const int x0 = (tt % nx) * 32, y0 = (tt / nx) * 32;
    const int tx = threadIdx.x & 31, ty = threadIdx.x >> 5;  // 32 x 8
#pragma unroll
    for (int i = 0; i < 4; ++i)
        t[ty + i * 8][tx] = W[(size_t)(y0 + ty + i * 8) * N + x0 + tx];
    __syncthreads();
#pragma unroll
    for (int i = 0; i < 4; ++i) {
        const int n = x0 + ty + i * 8;
        int dst = n;
        if (isq) {                                    // Q|K|V column-blocking
            const int hh = n / 192, r = n % 192;
            dst = (r < 64) ? hh * 64 + r
                : (r < 128) ? 1024 + hh * 64 + (r - 64)
                            : 2048 + hh * 64 + (r - 128);
        }
        float v = t[tx][ty + i * 8];
        if (isq && dst < 1024) v *= 0.18033688f;      // 0.125 * log2(e)
        WT[(size_t)dst * DD + y0 + tx] = f2bf(v);
    }
}

// ---------------------------------------------------------------------------
// 256x256 deep-pipelined GEMM (qkv):  C[M,N] = A[M,K] * B[K,N].
// BK=64, 8 waves (2M x 4N), per-wave C 128x64 (acc 8x4).  ONE barrier per
// K-tile, prefetch-after-barrier; LDS XOR-swizzled 16B chunks via gload src.
// Epilogue split:
//   n0 <  2048 (Q/K blocks): normal bf16 C-write into qkv.
//   n0 >= 2048 (V blocks)  : NO C-write; transpose 256x256 tile through LDS
//     and write vt[(b*16+h)*64+dk][s] coalesced.  Replaces transpose_v.
// XCD swizzle: 1D grid (nwg%8==0), chunk = nwg/8.
// LDS: 135168 B dynamic (main loop uses first 128 KiB).
// ---------------------------------------------------------------------------
__global__ __launch_bounds__(512, 2)
void gemm256(const u16* __restrict__ A, const u16* __restrict__ BT,
             u16* __restrict__ C, u16* __restrict__ vt, int M, int N, int K, int nbx)
{
    extern __shared__ __align__(16) u16 smem[];

    const int bid = blockIdx.x;
    const int chunk = (int)gridDim.x >> 3;
    const int swz = (bid & 7) * chunk + (bid >> 3);
    const int bxs = swz % nbx, bys = swz / nbx;

    const int tid = threadIdx.x;
    const int lane = tid & 63;
    const int wv = tid >> 6;
    const int quad = lane >> 4, l16 = lane & 15;
    const int wm = wv >> 2, wn = wv & 3;          // 2 x 4 wave grid
    const int m0 = bys * 256, n0 = bxs * 256;
    const int sw = l16 & 7;

    // staging map: per call 512 thr x 16B = 8 KiB = 64 rows of 128B.
    const int srow = tid >> 3, pc = tid & 7, lc = pc ^ (srow & 7);
    const u16* agp = A  + (size_t)(m0 + srow) * K + lc * 8;
    const u16* bgp = BT + (size_t)(n0 + srow) * K + lc * 8;
    u16* const asw = smem +         srow * 64 + pc * 8;   // + buf*16384 + s*4096
    u16* const bsw = smem + 32768 + srow * 64 + pc * 8;

    auto stage = [&](int buf, int k0) {
#pragma unroll
        for (int s = 0; s < 4; ++s)
            async_cp16(asw + buf * 16384 + s * 4096, agp + (size_t)(s * 64) * K + k0);
#pragma unroll
        for (int s = 0; s < 4; ++s)
            async_cp16(bsw + buf * 16384 + s * 4096, bgp + (size_t)(s * 64) * K + k0);
    };

    f32x4 acc[8][4];
#pragma unroll
    for (int i = 0; i < 8; ++i)
#pragma unroll
        for (int j = 0; j < 4; ++j) acc[i][j] = {0.f, 0.f, 0.f, 0.f};

    stage(0, 0);   // prologue

    const int NT = K / 64;
    for (int t = 0; t < NT; ++t) {
        const int p = t & 1;
        asm volatile("s_waitcnt vmcnt(0) lgkmcnt(0)\n\ts_barrier" ::: "memory");
        if (t + 1 < NT) stage(p ^ 1, (t + 1) * 64);

        const u16* Ab = smem +         p * 16384;
        const u16* Bb = smem + 32768 + p * 16384;

#pragma unroll
        for (int ks = 0; ks < 2; ++ks) {
            bf16x8 bfr[4];
#pragma unroll
            for (int nt = 0; nt < 4; ++nt)
                bfr[nt] = *(const bf16x8*)&Bb[(wn * 64 + nt * 16 + l16) * 64 + (((ks * 4 + quad) ^ sw) << 3)];
#pragma unroll
            for (int mt = 0; mt < 8; ++mt) {
                bf16x8 af = *(const bf16x8*)&Ab[(wm * 128 + mt * 16 + l16) * 64 + (((ks * 4 + quad) ^ sw) << 3)];
#pragma unroll
                for (int nt = 0; nt < 4; ++nt)
                    acc[mt][nt] = __builtin_amdgcn_mfma_f32_16x16x32_bf16(af, bfr[nt], acc[mt][nt], 0, 0, 0);
            }
        }
    }

    if (vt && n0 >= 2048) {
        // ---- V block: transpose through LDS, write vt only ----
        __syncthreads();   // all waves done with K-loop LDS reads
        u16* tb = smem;    // vtile[v_local][m_local], row stride 264 u16
#pragma unroll
        for (int mt = 0; mt < 8; ++mt)
#pragma unroll
            for (int nt = 0; nt < 4; ++nt) {
                const int vl = wn * 64 + nt * 16 + l16;
                const int ml = wm * 128 + mt * 16 + quad * 4;
                uint2 w;
                w.x = (u32)f2bf(acc[mt][nt][0]) | ((u32)f2bf(acc[mt][nt][1]) << 16);
                w.y = (u32)f2bf(acc[mt][nt][2]) | ((u32)f2bf(acc[mt][nt][3]) << 16);
                *(uint2*)(tb + (size_t)vl * 264 + ml) = w;
            }
        __syncthreads();
        const int vl = tid >> 1, half = tid & 1;
        const int b16 = (m0 >> 11) * 16;                 // batch*16
        const int hh = ((n0 - 2048) >> 6) + (vl >> 6);   // head
        const int dk = vl & 63;
        u16* dst = vt + ((size_t)(b16 + hh) * 64 + dk) * SS + (m0 & 2047) + half * 128;
        const u16* src = tb + (size_t)vl * 264 + half * 128;
#pragma unroll
        for (int j = 0; j < 16; ++j)
            *(uint4*)(dst + j * 8) = *(const uint4*)(src + j * 8);
    } else {
        // ---- Q/K block: normal bf16 C-write ----
#pragma unroll
        for (int mt = 0; mt < 8; ++mt)
#pragma unroll
            for (int r = 0; r < 4; ++r) {
                const size_t row = m0 + wm * 128 + mt * 16 + quad * 4 + r;
                u16* cp = C + row * N + n0 + wn * 64 + l16;
#pragma unroll
                for (int nt = 0; nt < 4; ++nt) cp[nt * 16] = f2bf(acc[mt][nt][r]);
            }
    }
}

// ---------------------------------------------------------------------------
// Out-projection GEMM on the 1-barrier dbuf schedule (R11/R12, passing).
// BM=128 x BN=NT, BK=64, 4 waves.  Double-buffered LDS (48 KiB at NT=64 ->
// 3 blocks/CU); prefetch(t+1) issued AFTER barrier(t).
// 1D grid + XCD swizzle (nwg%8==0).
// ---------------------------------------------------------------------------
template <int OUT_BF16, int NT>
__global__ __launch_bounds__(256)
void gemm_mfma(const u16* __restrict__ A, const u16* __restrict__ BT,
               void* __restrict__ Cv, int M, int N, int K, int nbx)
{
    constexpr int FR = NT / 32;    // B frags per wave per ks
    __shared__ u16 As[2][128 * 64];   // [m][64] swizzled, dbuf
    __shared__ u16 Bs[2][NT * 64];    // [n][64] swizzled, dbuf

    const int bid = blockIdx.x;
    const int chunk = (int)gridDim.x >> 3;
    const int swz = (bid & 7) * chunk + (bid >> 3);
    const int bxs = swz % nbx, bys = swz / nbx;

    const int tid = threadIdx.x;
    const int lane = tid & 63, wv = tid >> 6;
    const int quad = lane >> 4, l16 = lane & 15;
    const int m0 = bys * 128, n0 = bxs * NT;

    const int arow = wv * 32 + (lane >> 3);
    const int pc   = lane & 7;
    const int lcA  = pc ^ (arow & 7);
    const u16* agp = A + (size_t)(m0 + arow) * K + lcA * 8;

    const int brow = (NT == 128) ? (wv * 32 + (lane >> 3)) : (wv * 8 + (lane >> 3));
    const int lcB  = pc ^ (brow & 7);
    const u16* bgp = BT + (size_t)(n0 + brow) * K + lcB * 8;

    const int aoff = arow * 64 + pc * 8;
    const int boff = brow * 64 + pc * 8;

    auto stage = [&](int buf, int k0) {
#pragma unroll
        for (int s = 0; s < 4; ++s)
            async_cp16(&As[buf][aoff + s * 8 * 64], agp + (size_t)(s * 8) * K + k0);
        if constexpr (NT == 128) {
#pragma unroll
            for (int s = 0; s < 4; ++s)
                async_cp16(&Bs[buf][boff + s * 8 * 64], bgp + (size_t)(s * 8) * K + k0);
        } else {
#pragma unroll
            for (int s = 0; s < 2; ++s)
                async_cp16(&Bs[buf][boff + s * 32 * 64], bgp + (size_t)(s * 32) * K + k0);
        }
    };

    const int moff = (wv >> 1) * 64, noff = (wv & 1) * (NT / 2);

    f32x4 acc[4][FR];
#pragma unroll
    for (int i = 0; i < 4; ++i)
#pragma unroll
        for (int j = 0; j < FR; ++j) acc[i][j] = {0.f, 0.f, 0.f, 0.f};

    const int swf = l16 & 7;   // frag-read swizzle key

    stage(0, 0);   // prologue

    const int NTILES = K / 64;
    for (int t = 0; t < NTILES; ++t) {
        const int p = t & 1;
        // stage(t) drained (issued a full K-tile of compute ago); prior reads done
        asm volatile("s_waitcnt vmcnt(0) lgkmcnt(0)\n\ts_barrier" ::: "memory");
        if (t + 1 < NTILES) stage(p ^ 1, (t + 1) * 64);

        const u16* Ab = As[p];
        const u16* Bb = Bs[p];

#pragma unroll
        for (int ks = 0; ks < 2; ++ks) {
            bf16x8 af[4], bfr[FR];
#pragma unroll
            for (int tt = 0; tt < 4; ++tt)
                af[tt] = *(const bf16x8*)&Ab[(moff + tt * 16 + l16) * 64 + (((ks * 4 + quad) ^ swf) << 3)];
#pragma unroll
            for (int tt = 0; tt < FR; ++tt)
                bfr[tt] = *(const bf16x8*)&Bb[(noff + tt * 16 + l16) * 64 + (((ks * 4 + quad) ^ swf) << 3)];
#pragma unroll
            for (int mt = 0; mt < 4; ++mt)
#pragma unroll
                for (int nt = 0; nt < FR; ++nt)
                    acc[mt][nt] = __builtin_amdgcn_mfma_f32_16x16x32_bf16(af[mt], bfr[nt], acc[mt][nt], 0, 0, 0);
        }
    }

    // D layout: row = quad*4+reg, col = l16 (within each 16x16 frag)
#pragma unroll
    for (int mt = 0; mt < 4; ++mt)
#pragma unroll
        for (int r = 0; r < 4; ++r) {
            const size_t row = m0 + moff + mt * 16 + quad * 4 + r;
            if (OUT_BF16) {
                u16* cp = (u16*)Cv + row * N + n0 + noff + l16;
#pragma unroll
                for (int nt = 0; nt < FR; ++nt) cp[nt * 16] = f2bf(acc[mt][nt][r]);
            } else {
                float* cp = (float*)Cv + row * N + n0 + noff + l16;
#pragma unroll
                for (int nt = 0; nt < FR; ++nt) cp[nt * 16] = acc[mt][nt][r];
            }
        }
}

// ---------------------------------------------------------------------------
// MFMA flash attention, column-blocked qkv — R12 body EXACTLY (measured best:
// attn 48.0 us, total 179.4).  Softmax fused into the PV loop per-kn AFTER a
// full QK cluster: the sf[2][4] array keeps 8 INDEPENDENT QK-MFMA chains
// (ILP reservoir — R13's full per-kn fusion made the chain dependent and
// regressed 48->57 us); exp2/pack of kn then feeds kn's 8 PV MFMAs directly,
// pipelining VALU(kn+1) under MFMA(kn).  One barrier per k-tile with
// prefetch-after-barrier; fixed-max softmax (Q pre-scaled by dk^-0.5*log2e);
// l = fp32 sum of exp2 outputs.  LDS 64 KiB -> 2 blocks/CU.
// ---------------------------------------------------------------------------
__global__ __launch_bounds__(512, 4)
void attn_mfma(const u16* __restrict__ qkv, const u16* __restrict__ vt, u16* __restrict__ o)
{
    __shared__ __align__(16) u16 smem[32768];   // 64 KiB flat; Ks: [grp*2+p]*4096, Vs: +16384

    const int tid = threadIdx.x;
    const int lane = tid & 63, wv = tid >> 6;       // 8 waves
    const int grp = wv >> 2, w4 = wv & 3;
    const int quad = lane >> 4, l16 = lane & 15;
    const int bx = blockIdx.x;
    const int bh = bx & 31, qt = bx >> 5;
    const int h = bh & 15, b = bh >> 4;

    const size_t base = (size_t)b * SS * N3;
    const int q0 = qt * 128 + w4 * 32;
    const int sw = l16 & 7;          // row-swizzle key for frag reads

    // Q frags (A-operand: m=l16, k=quad*8+j), [mtile][kstep] — pre-scaled Q
    bf16x8 qf[2][2];
#pragma unroll
    for (int mt = 0; mt < 2; ++mt)
#pragma unroll
        for (int ks = 0; ks < 2; ++ks)
            qf[mt][ks] = *(const bf16x8*)(qkv + base + h * 64 + (size_t)(q0 + mt * 16 + l16) * N3 + ks * 32 + quad * 8);

    f32x4 po[2][4];   // O^T accum: [q-blk mt][d-blk nt], d=quad*4+r, q=l16
#pragma unroll
    for (int mt = 0; mt < 2; ++mt)
#pragma unroll
        for (int nt = 0; nt < 4; ++nt) po[mt][nt] = {0.f, 0.f, 0.f, 0.f};
    float lrun[2] = {0.f, 0.f};

    // staging map: per call 64 lanes x 16B = 8 rows of 128B; lane -> row lrow,
    // phys chunk pc8; swizzle folded into SOURCE: logical chunk = pc8 ^ (row&7).
    const int lrow = lane >> 3, pc8 = lane & 7, lc = pc8 ^ lrow;
    const int srow = w4 * 16;
    const int kt0 = grp * 16;        // this group's first k-tile

    const u16* kgp = qkv + base + 1024 + h * 64 + (size_t)(kt0 * 64 + srow + lrow) * N3 + lc * 8;
    const u16* vgp = vt + ((size_t)bh * 64 + srow + lrow) * SS + kt0 * 64 + lc * 8;

    u16* const ksA = smem + (grp * 2) * 4096 + (srow + lrow) * 64 + pc8 * 8;
    u16* const ksB = ksA + 4096;
    u16* const vsA = smem + 16384 + (grp * 2) * 4096 + (srow + lrow) * 64 + pc8 * 8;
    u16* const vsB = vsA + 4096;

    // prologue: stage tile kt0 into buffer A
    async_cp16(ksA,       kgp);
    async_cp16(ksA + 512, kgp + (size_t)8 * N3);
    async_cp16(vsA,       vgp);
    async_cp16(vsA + 512, vgp + (size_t)8 * SS);

    for (int it = 0; it < 16; ++it) {
        const int p = it & 1;
        // stage(it) done (issued a full tile ago); all waves past PV(it-1)
        asm volatile("s_waitcnt vmcnt(0) lgkmcnt(0)\n\ts_barrier" ::: "memory");
        if (it < 15) {
            const size_t ko = (size_t)(it + 1) * 64;
            u16* kb = p ? ksA : ksB;
            u16* vb = p ? vsA : vsB;
            async_cp16(kb,       kgp + ko * N3);
            async_cp16(kb + 512, kgp + ko * N3 + (size_t)8 * N3);
            async_cp16(vb,       vgp + ko);
            async_cp16(vb + 512, vgp + ko + (size_t)8 * SS);
        }
        const u16* kbuf = smem + (grp * 2 + p) * 4096;
        const u16* vbuf = smem + 16384 + (grp * 2 + p) * 4096;

        // ---- S^T = K * Q^T : sf[mt][kn] holds keys kn*16+quad*4+r, q = l16
        f32x4 sf[2][4];
#pragma unroll
        for (int mt = 0; mt < 2; ++mt)
#pragma unroll
            for (int kn = 0; kn < 4; ++kn) sf[mt][kn] = {0.f, 0.f, 0.f, 0.f};
        __builtin_amdgcn_s_setprio(1);
#pragma unroll
        for (int ks = 0; ks < 2; ++ks)
#pragma unroll
            for (int kn = 0; kn < 4; ++kn) {
                bf16x8 kf = *(const bf16x8*)&kbuf[(kn * 16 + l16) * 64 + (((ks * 4 + quad) ^ sw) << 3)];
#pragma unroll
                for (int mt = 0; mt < 2; ++mt)
                    sf[mt][kn] = __builtin_amdgcn_mfma_f32_16x16x32_bf16(kf, qf[mt][ks], sf[mt][kn], 0, 0, 0);
            }
        __builtin_amdgcn_s_setprio(0);

        // ---- fused softmax + PV, per-kn: exp2/pack feeds the kn's MFMAs
        // directly; exp2 of kn+1 pipelines under MFMA of kn (separate pipes).
        __builtin_amdgcn_s_setprio(1);
#pragma unroll
        for (int kn = 0; kn < 4; ++kn) {
            bf16x4 vf[4];
#pragma unroll
            for (int nt = 0; nt < 4; ++nt)
                vf[nt] = *(const bf16x4*)&vbuf[(nt * 16 + l16) * 64 + (((2 * kn + (quad >> 1)) ^ sw) << 3) + ((quad & 1) << 2)];
#pragma unroll
            for (int mt = 0; mt < 2; ++mt) {
                const float p0 = fast_exp2(sf[mt][kn][0]);
                const float p1 = fast_exp2(sf[mt][kn][1]);
                const float p2 = fast_exp2(sf[mt][kn][2]);
                const float p3 = fast_exp2(sf[mt][kn][3]);
                lrun[mt] += (p0 + p1) + (p2 + p3);
                union { bf16x4 v; u32 w[2]; } pu;
                pu.w[0] = __builtin_amdgcn_perm(__float_as_uint(p1), __float_as_uint(p0), 0x07060302u);
                pu.w[1] = __builtin_amdgcn_perm(__float_as_uint(p3), __float_as_uint(p2), 0x07060302u);
#pragma unroll
                for (int nt = 0; nt < 4; ++nt)
                    po[mt][nt] = mfma16(vf[nt], pu.v, po[mt][nt]);
            }
        }
        __builtin_amdgcn_s_setprio(0);
    }

    __syncthreads();   // all K/V reads done; smem reusable as f32 scratch

    // quad-reduce l (keys split across quads) — both groups
#pragma unroll
    for (int mt = 0; mt < 2; ++mt) {
        lrun[mt] += __shfl_xor(lrun[mt], 16, 64);
        lrun[mt] += __shfl_xor(lrun[mt], 32, 64);
    }

    // cross-group combine: group 1 -> LDS -> group 0 adds
    float* xch = (float*)smem;       // [w4*64+lane][36] f32, 36 KiB
    if (grp == 1) {
        float* d = xch + (w4 * 64 + lane) * 36;
#pragma unroll
        for (int mt = 0; mt < 2; ++mt)
#pragma unroll
            for (int nt = 0; nt < 4; ++nt)
                *(f32x4*)(d + mt * 16 + nt * 4) = po[mt][nt];
        d[32] = lrun[0]; d[33] = lrun[1];
    }
    __syncthreads();
    if (grp == 0) {
        const float* s = xch + (w4 * 64 + lane) * 36;
#pragma unroll
        for (int mt = 0; mt < 2; ++mt)
#pragma unroll
            for (int nt = 0; nt < 4; ++nt)
                po[mt][nt] = po[mt][nt] + *(const f32x4*)(s + mt * 16 + nt * 4);
        lrun[0] += s[32]; lrun[1] += s[33];

        // O^T frag: q = l16 (lane-uniform l), d = nt*16 + quad*4 + r
#pragma unroll
        for (int mt = 0; mt < 2; ++mt) {
            const float linv = 1.f / lrun[mt];
            const size_t row = (size_t)b * SS + q0 + mt * 16 + l16;
#pragma unroll
            for (int nt = 0; nt < 4; ++nt) {
                const u32 h0 = (u32)f2bf(po[mt][nt][0] * linv) | ((u32)f2bf(po[mt][nt][1] * linv) << 16);
                const u32 h1 = (u32)f2bf(po[mt][nt][2] * linv) | ((u32)f2bf(po[mt][nt][3] * linv) << 16);
                uint2 wp; wp.x = h0; wp.y = h1;
                *(uint2*)(o + row * DD + h * 64 + nt * 16 + quad * 4) = wp;
            }
        }
    }
}

// ---------------------------------------------------------------------------
extern "C" void kernel_launch(void* const* d_in, const int* in_sizes, int n_in,
                              void* d_out, int out_size, void* d_ws, size_t ws_size,
                              hipStream_t stream)
{
    const float* query  = (const float*)d_in[0];
    const float* posemb = (const float*)d_in[1];
    const float* w_qkv  = (const float*)d_in[2];
    const float* w_out  = (const float*)d_in[3];
    float* out = (float*)d_out;

    u16* xb    = (u16*)d_ws;                       // [4096,1024] bf16
    u16* wqkvT = xb    + (size_t)4096 * 1024;      // [3072,1024] (row-permuted)
    u16* woutT = wqkvT + (size_t)3072 * 1024;      // [1024,1024]
    u16* qkv   = woutT + (size_t)1024 * 1024;      // [4096,3072] Q|K|(V unused)
    u16* ob    = qkv   + (size_t)4096 * 3072;      // [4096,1024]
    u16* vtb   = ob    + (size_t)4096 * 1024;      // [32,64,2048] V^T

    // allow 132 KiB dynamic LDS for gemm256 (one-time, host-side, capture-safe)
    static bool lds_init = false;
    if (!lds_init) {
        hipFuncSetAttribute((const void*)gemm256,
                            hipFuncAttributeMaxDynamicSharedMemorySize, 135168);
        lds_init = true;
    }

    // fused: prep_x + both weight transposes (wqkvT rows permuted to Q|K|V)
    prep_all<<<8192, 256, 0, stream>>>(query, posemb, w_qkv, w_out, xb, wqkvT, woutT);

    // qkv = x @ w_qkv (M=4096, N=3072, K=1024): Q/K -> qkv, V -> vt (transposed)
    gemm256<<<192, 512, 135168, stream>>>(xb, wqkvT, qkv, vtb, 4096, N3, DD, N3 / 256);

    // flash attention -> ob [4096,1024] bf16  (512 blocks x 512 thr, key-split)
    attn_mfma<<<dim3(512, 1, 1), 512, 0, stream>>>(qkv, vtb, ob);

    // out = ob @ w_out  (M=4096, N=1024, K=1024), fp32 out, 1-barrier dbuf
    gemm_mfma<0, 64><<<512, 256, 0, stream>>>(ob, woutT, (void*)out, 4096, DD, DD, DD / 64);
}